// Round 5
// baseline (368.937 us; speedup 1.0000x reference)
//
#include <hip/hip_runtime.h>
#include <hip/hip_bf16.h>
#include <math.h>

#define TSEQ 2048
#define NB 2
#define DM 1024
#define NH 16
#define DHD 64

typedef __attribute__((ext_vector_type(8))) __bf16 bf16x8;
typedef __attribute__((ext_vector_type(8))) short s16x8;
typedef __attribute__((ext_vector_type(4))) float f32x4;

__device__ __forceinline__ bf16x8 ld_bf16x8(const void* p) {
  s16x8 v = *reinterpret_cast<const s16x8*>(p);
  return __builtin_bit_cast(bf16x8, v);
}

#define GLL16(g, l) __builtin_amdgcn_global_load_lds( \
    (const __attribute__((address_space(1))) void*)(g), \
    (__attribute__((address_space(3))) void*)(l), 16, 0, 0)

// ---------- transpose + cast fp32 -> bf16 : out[C][R] = in[R][C] ----------
__global__ __launch_bounds__(256) void k_transpose_cast(
    const float* __restrict__ in, __hip_bfloat16* __restrict__ out,
    int R, int C) {
  __shared__ float t[32][33];
  const int tx = threadIdx.x, ty = threadIdx.y;
  const int c0 = blockIdx.x * 32, r0 = blockIdx.y * 32;
#pragma unroll
  for (int j = 0; j < 4; ++j)
    t[ty + j * 8][tx] = in[(size_t)(r0 + ty + j * 8) * C + c0 + tx];
  __syncthreads();
#pragma unroll
  for (int j = 0; j < 4; ++j) {
    const int oc = ty + j * 8;
    out[(size_t)(c0 + oc) * R + r0 + tx] = __float2bfloat16(t[tx][oc]);
  }
}

// ---------- elementwise cast fp32 -> bf16 (exact-multiple sizes) ----------
__global__ __launch_bounds__(256) void k_cast_bf16(
    const float* __restrict__ in, __hip_bfloat16* __restrict__ out) {
  const int i = (blockIdx.x * 256 + threadIdx.x) * 4;
  const float4 v = *reinterpret_cast<const float4*>(in + i);
  struct B4 { __hip_bfloat16 a, b, c, d; } o;
  o.a = __float2bfloat16(v.x); o.b = __float2bfloat16(v.y);
  o.c = __float2bfloat16(v.z); o.d = __float2bfloat16(v.w);
  *reinterpret_cast<B4*>(out + i) = o;
}

// ---------- LayerNorm rows of [4096][1024], fp32 in -> bf16 out ----------
__global__ __launch_bounds__(256) void k_layernorm(
    const float* __restrict__ x, const float* __restrict__ g,
    const float* __restrict__ b, __hip_bfloat16* __restrict__ out) {
  const int row = blockIdx.x, tid = threadIdx.x;
  const float4 v = reinterpret_cast<const float4*>(x + (size_t)row * DM)[tid];
  float s = v.x + v.y + v.z + v.w;
  __shared__ float r1[4], r2[4];
#pragma unroll
  for (int off = 32; off; off >>= 1) s += __shfl_xor(s, off);
  if ((tid & 63) == 0) r1[tid >> 6] = s;
  __syncthreads();
  const float mu = (r1[0] + r1[1] + r1[2] + r1[3]) * (1.f / DM);
  const float dx = v.x - mu, dy = v.y - mu, dz = v.z - mu, dw = v.w - mu;
  float q = dx * dx + dy * dy + dz * dz + dw * dw;
#pragma unroll
  for (int off = 32; off; off >>= 1) q += __shfl_xor(q, off);
  if ((tid & 63) == 0) r2[tid >> 6] = q;
  __syncthreads();
  const float rs = rsqrtf((r2[0] + r2[1] + r2[2] + r2[3]) * (1.f / DM) + 1e-5f);
  const float4 gv = reinterpret_cast<const float4*>(g)[tid];
  const float4 bv = reinterpret_cast<const float4*>(b)[tid];
  struct B4 { __hip_bfloat16 a, b, c, d; } o;
  o.a = __float2bfloat16(dx * rs * gv.x + bv.x);
  o.b = __float2bfloat16(dy * rs * gv.y + bv.y);
  o.c = __float2bfloat16(dz * rs * gv.z + bv.z);
  o.d = __float2bfloat16(dw * rs * gv.w + bv.w);
  reinterpret_cast<B4*>(out + (size_t)row * DM)[tid] = o;
}

// ---------- generic 128x128 bf16 MFMA GEMM, C = A[M][K] * BT[N][K]^T ----------
// MODE 0: QKV epilogue  MODE 1: R epilogue  MODE 2: fp32 out epilogue
template <int MODE>
__global__ __launch_bounds__(256) void k_gemm_bt(
    const __hip_bfloat16* __restrict__ A, const __hip_bfloat16* __restrict__ BT,
    int M, int N, int K, float* __restrict__ outF,
    __hip_bfloat16* __restrict__ o_qw, __hip_bfloat16* __restrict__ o_qr,
    __hip_bfloat16* __restrict__ o_k, __hip_bfloat16* __restrict__ o_vT,
    const float* __restrict__ rwb, const float* __restrict__ rrb,
    __hip_bfloat16* __restrict__ o_rT) {
  __shared__ __align__(16) __hip_bfloat16 As[128 * 32];
  __shared__ __align__(16) __hip_bfloat16 Bs[128 * 32];
  const int tid = threadIdx.x, lane = tid & 63;
  const int ntn = N >> 7;
  const int m0 = (blockIdx.x / ntn) * 128, n0 = (blockIdx.x % ntn) * 128;
  const int wid = tid >> 6;
  const int wr = (wid >> 1) * 64, wc = (wid & 1) * 64;
  const int fr = lane & 15, fq = lane >> 4;
  const int srow = tid >> 2, scol = (tid & 3) * 8;
  const __hip_bfloat16* aSrc = A + (size_t)(m0 + srow) * K + scol;
  const __hip_bfloat16* bSrc = BT + (size_t)(n0 + srow) * K + scol;
  char* aDst = (char*)As + (tid - lane) * 16;
  char* bDst = (char*)Bs + (tid - lane) * 16;
  f32x4 acc[4][4] = {};
  for (int k0 = 0; k0 < K; k0 += 32) {
    GLL16(aSrc + k0, aDst);
    GLL16(aSrc + (size_t)64 * K + k0, aDst + 4096);
    GLL16(bSrc + k0, bDst);
    GLL16(bSrc + (size_t)64 * K + k0, bDst + 4096);
    __syncthreads();
    bf16x8 af[4], bfr[4];
#pragma unroll
    for (int mi = 0; mi < 4; ++mi)
      af[mi] = ld_bf16x8(As + (wr + mi * 16 + fr) * 32 + fq * 8);
#pragma unroll
    for (int ni = 0; ni < 4; ++ni)
      bfr[ni] = ld_bf16x8(Bs + (wc + ni * 16 + fr) * 32 + fq * 8);
#pragma unroll
    for (int mi = 0; mi < 4; ++mi)
#pragma unroll
      for (int ni = 0; ni < 4; ++ni)
        acc[mi][ni] = __builtin_amdgcn_mfma_f32_16x16x32_bf16(
            af[mi], bfr[ni], acc[mi][ni], 0, 0, 0);
    __syncthreads();
  }
#pragma unroll
  for (int mi = 0; mi < 4; ++mi) {
#pragma unroll
    for (int ni = 0; ni < 4; ++ni) {
#pragma unroll
      for (int j = 0; j < 4; ++j) {
        const int r = m0 + wr + mi * 16 + fq * 4 + j;
        const int c = n0 + wc + ni * 16 + fr;
        const float v = acc[mi][ni][j];
        if (MODE == 2) {
          outF[(size_t)r * N + c] = v;
        } else if (MODE == 1) {
          const int h = c >> 6, d = c & 63;
          o_rT[((size_t)h * TSEQ + r) * DHD + d] = __float2bfloat16(v);
        } else {
          const int t = r >> 1, bb = r & 1;
          if (c < 1024) {
            const int h = c >> 6, d = c & 63;
            const size_t o = (((size_t)(bb * NH + h)) * TSEQ + t) * DHD + d;
            o_qw[o] = __float2bfloat16(v + rwb[c]);
            o_qr[o] = __float2bfloat16(v + rrb[c]);
          } else if (c < 2048) {
            const int e = c - 1024, h = e >> 6, d = e & 63;
            o_k[(((size_t)(bb * NH + h)) * TSEQ + t) * DHD + d] = __float2bfloat16(v);
          } else {
            const int e = c - 2048, h = e >> 6, d = e & 63;
            o_vT[(((size_t)(bb * NH + h)) * DHD + d) * TSEQ + t] = __float2bfloat16(v);
          }
        }
      }
    }
  }
}

// ---------- fused causal rel-attention, swapped core (hardened) ----------
// Wave = one (head, 16-row q-tile). S^T = mfma(K,Q): lane owns q-row fr,
// koffs {16n+4fq+j}; softmax in-register + 4 xor-butterflies.
// Band: R3's PROVEN production mfma(Qr,R) -> braw[q=4fq+j][m=16pp+fr];
// swapped consumer reads braw[fr][15-fr+koff] (trivial index).
// PV also swapped: O^T[d][q=fr] = mfma(V_frag, P_frag) -> alpha & 1/l are
// per-lane scalars, zero broadcast shuffles. Barrier-free (all LDS per-wave).
__global__ __launch_bounds__(256) void k_attn(
    const __hip_bfloat16* __restrict__ qw, const __hip_bfloat16* __restrict__ qr,
    const __hip_bfloat16* __restrict__ kb, const __hip_bfloat16* __restrict__ vT,
    const __hip_bfloat16* __restrict__ rT, __hip_bfloat16* __restrict__ av) {
  const int tid = threadIdx.x, w = tid >> 6, lane = tid & 63;
  const int fr = lane & 15, fq = lane >> 4;
  const int bid = blockIdx.x;
  const int xcd = bid & 7, slot = bid >> 3;     // XCD-local heads, LPT slots
  const int bh = xcd * 4 + w;
  const int bb = bh >> 4, h = bh & 15;
  const int p = 127 - slot;                     // big tiles first
  const int iw0 = p * 16;
  const int nk = (p >> 2) + 1;
  const size_t bhs = (size_t)bh;
  const __hip_bfloat16* Kp = kb + bhs * TSEQ * DHD;
  const __hip_bfloat16* Vt = vT + bhs * DHD * TSEQ;
  const __hip_bfloat16* Rp = rT + (size_t)h * TSEQ * DHD;
  __shared__ float braw[4][16][86];
  __shared__ __align__(16) __hip_bfloat16 plq[4][16][72];
  const f32x4 zero = {0.f, 0.f, 0.f, 0.f};

  const __hip_bfloat16* qwp = qw + (bhs * TSEQ + iw0 + fr) * DHD + fq * 8;
  const __hip_bfloat16* qrp = qr + (bhs * TSEQ + iw0 + fr) * DHD + fq * 8;
  const bf16x8 qwf0 = ld_bf16x8(qwp), qwf1 = ld_bf16x8(qwp + 32);
  const bf16x8 qrf0 = ld_bf16x8(qrp), qrf1 = ld_bf16x8(qrp + 32);

  f32x4 o[4] = {};
  float mrow = -INFINITY, lrow = 0.f;

  for (int kt = 0; kt < nk; ++kt) {
    const int j0 = kt * 64;
    // ---- S^T = mfma(K, Q): st[n][j] = S[q=fr][koff=16n+4fq+j] ----
    f32x4 st[4];
    const __hip_bfloat16* kp0 = Kp + (size_t)(j0 + fr) * DHD + fq * 8;
#pragma unroll
    for (int n = 0; n < 4; ++n) {
      st[n] = __builtin_amdgcn_mfma_f32_16x16x32_bf16(ld_bf16x8(kp0 + n * 1024), qwf0, zero, 0, 0, 0);
      st[n] = __builtin_amdgcn_mfma_f32_16x16x32_bf16(ld_bf16x8(kp0 + n * 1024 + 32), qwf1, st[n], 0, 0, 0);
    }
    // ---- band production (R3-proven orientation): braw[q=4fq+j][m=16pp+fr] ----
    const int base = TSEQ - 16 - iw0 + j0;
#pragma unroll
    for (int pp = 0; pp < 5; ++pp) {
      int idx = base + pp * 16 + fr;
      idx = idx < 0 ? 0 : (idx > TSEQ - 1 ? TSEQ - 1 : idx);  // clamped => masked region only
      const __hip_bfloat16* rp = Rp + (size_t)idx * DHD + fq * 8;
      f32x4 br = __builtin_amdgcn_mfma_f32_16x16x32_bf16(qrf0, ld_bf16x8(rp), zero, 0, 0, 0);
      br = __builtin_amdgcn_mfma_f32_16x16x32_bf16(qrf1, ld_bf16x8(rp + 32), br, 0, 0, 0);
#pragma unroll
      for (int j = 0; j < 4; ++j) braw[w][fq * 4 + j][pp * 16 + fr] = br[j];
    }
    // ---- scores + in-register online softmax (q = fr) ----
    const int thr = iw0 + fr - j0;              // unmasked iff koff <= thr
    const float* brd = &braw[w][fr][15 - fr];   // brd[koff] = BD term
    float mx = -INFINITY;
#pragma unroll
    for (int n = 0; n < 4; ++n) {
#pragma unroll
      for (int j = 0; j < 4; ++j) {
        const int koff = 16 * n + 4 * fq + j;
        const float s = (koff > thr) ? -INFINITY : (st[n][j] + brd[koff]) * 0.125f;
        st[n][j] = s;
        mx = fmaxf(mx, s);
      }
    }
    mx = fmaxf(mx, __shfl_xor(mx, 16));
    mx = fmaxf(mx, __shfl_xor(mx, 32));
    const float mn = fmaxf(mrow, mx);
    const float al = __expf(mrow - mn);
    mrow = mn;
    float rs = 0.f;
#pragma unroll
    for (int n = 0; n < 4; ++n)
#pragma unroll
      for (int j = 0; j < 4; ++j) {
        const float pv = __expf(st[n][j] - mn);
        st[n][j] = pv;
        rs += pv;
      }
    rs += __shfl_xor(rs, 16);
    rs += __shfl_xor(rs, 32);
    lrow = lrow * al + rs;
#pragma unroll
    for (int nd = 0; nd < 4; ++nd) o[nd] *= al;   // per-lane scalar (q = fr)
    // ---- P store: P[q=fr][koff] ----
    __hip_bfloat16* pwv = &plq[w][fr][4 * fq];
#pragma unroll
    for (int n = 0; n < 4; ++n)
#pragma unroll
      for (int j = 0; j < 4; ++j)
        pwv[16 * n + j] = __float2bfloat16(st[n][j]);
    // ---- O^T += V^T . P^T : o[nd][j] = O[d=16nd+4fq+j][q=fr] ----
#pragma unroll
    for (int c = 0; c < 2; ++c) {
      const bf16x8 pf = ld_bf16x8(&plq[w][fr][8 * fq + 32 * c]);
#pragma unroll
      for (int nd = 0; nd < 4; ++nd) {
        const __hip_bfloat16* vp = Vt + (size_t)(16 * nd + fr) * TSEQ + j0 + 32 * c + 8 * fq;
        o[nd] = __builtin_amdgcn_mfma_f32_16x16x32_bf16(ld_bf16x8(vp), pf, o[nd], 0, 0, 0);
      }
    }
  }
  // ---- epilogue: per-lane 1/l, packed 8B stores; row i = iw0+fr ----
  const float linv = 1.f / lrow;
  const int i = iw0 + fr;
  struct B4 { __hip_bfloat16 a, b, c, d; };
#pragma unroll
  for (int nd = 0; nd < 4; ++nd) {
    B4 pack;
    pack.a = __float2bfloat16(o[nd][0] * linv);
    pack.b = __float2bfloat16(o[nd][1] * linv);
    pack.c = __float2bfloat16(o[nd][2] * linv);
    pack.d = __float2bfloat16(o[nd][3] * linv);
    *reinterpret_cast<B4*>(av + ((size_t)i * NB + bb) * DM + h * DHD + 16 * nd + 4 * fq) = pack;
  }
}

extern "C" void kernel_launch(void* const* d_in, const int* in_sizes, int n_in,
                              void* d_out, int out_size, void* d_ws, size_t ws_size,
                              hipStream_t stream) {
  (void)in_sizes; (void)n_in; (void)out_size; (void)ws_size;
  const float* x    = (const float*)d_in[0];
  const float* pos  = (const float*)d_in[1];
  const float* ln_g = (const float*)d_in[2];
  const float* ln_b = (const float*)d_in[3];
  const float* Wqkv = (const float*)d_in[4];
  const float* Wr   = (const float*)d_in[5];
  const float* Wo   = (const float*)d_in[6];
  const float* rwb  = (const float*)d_in[7];
  const float* rrb  = (const float*)d_in[8];
  float* out = (float*)d_out;

  char* ws = (char*)d_ws;
  size_t off = 0;
  auto alloc = [&](size_t n) {
    char* p = ws + off; off += (n + 255) & ~(size_t)255; return p;
  };
  __hip_bfloat16* wqkvT = (__hip_bfloat16*)alloc((size_t)3072 * 1024 * 2);
  __hip_bfloat16* wrT   = (__hip_bfloat16*)alloc((size_t)1024 * 1024 * 2);
  __hip_bfloat16* woT   = (__hip_bfloat16*)alloc((size_t)1024 * 1024 * 2);
  __hip_bfloat16* posb  = (__hip_bfloat16*)alloc((size_t)2048 * 1024 * 2);
  __hip_bfloat16* xn    = (__hip_bfloat16*)alloc((size_t)4096 * 1024 * 2);
  __hip_bfloat16* qwb   = (__hip_bfloat16*)alloc((size_t)NB * NH * TSEQ * DHD * 2);
  __hip_bfloat16* qrb   = (__hip_bfloat16*)alloc((size_t)NB * NH * TSEQ * DHD * 2);
  __hip_bfloat16* kbb   = (__hip_bfloat16*)alloc((size_t)NB * NH * TSEQ * DHD * 2);
  __hip_bfloat16* vTb   = (__hip_bfloat16*)alloc((size_t)NB * NH * TSEQ * DHD * 2);
  __hip_bfloat16* rTb   = (__hip_bfloat16*)alloc((size_t)NH * TSEQ * DHD * 2);
  __hip_bfloat16* avb   = (__hip_bfloat16*)alloc((size_t)4096 * 1024 * 2);

  const dim3 tb(32, 8);
  k_transpose_cast<<<dim3(3072 / 32, 1024 / 32), tb, 0, stream>>>(Wqkv, wqkvT, 1024, 3072);
  k_transpose_cast<<<dim3(1024 / 32, 1024 / 32), tb, 0, stream>>>(Wr, wrT, 1024, 1024);
  k_transpose_cast<<<dim3(1024 / 32, 1024 / 32), tb, 0, stream>>>(Wo, woT, 1024, 1024);
  k_cast_bf16<<<(2048 * 1024) / 1024, 256, 0, stream>>>(pos, posb);
  k_layernorm<<<4096, 256, 0, stream>>>(x, ln_g, ln_b, xn);
  k_gemm_bt<0><<<32 * 24, 256, 0, stream>>>(xn, wqkvT, 4096, 3072, 1024,
      nullptr, qwb, qrb, kbb, vTb, rwb, rrb, nullptr);
  k_gemm_bt<1><<<16 * 8, 256, 0, stream>>>(posb, wrT, 2048, 1024, 1024,
      nullptr, nullptr, nullptr, nullptr, nullptr, nullptr, nullptr, rTb);
  k_attn<<<1024, 256, 0, stream>>>(qwb, qrb, kbb, vTb, rTb, avb);
  k_gemm_bt<2><<<32 * 8, 256, 0, stream>>>(avb, woT, 4096, 1024, 1024,
      out, nullptr, nullptr, nullptr, nullptr, nullptr, nullptr, nullptr);
}

// Round 6
// 322.459 us; speedup vs baseline: 1.1441x; 1.1441x over previous
//
#include <hip/hip_runtime.h>
#include <hip/hip_bf16.h>
#include <math.h>

#define TSEQ 2048
#define NB 2
#define DM 1024
#define NH 16
#define DHD 64

typedef __attribute__((ext_vector_type(8))) __bf16 bf16x8;
typedef __attribute__((ext_vector_type(8))) short s16x8;
typedef __attribute__((ext_vector_type(4))) float f32x4;

__device__ __forceinline__ bf16x8 ld_bf16x8(const void* p) {
  s16x8 v = *reinterpret_cast<const s16x8*>(p);
  return __builtin_bit_cast(bf16x8, v);
}

#define GLL16(g, l) __builtin_amdgcn_global_load_lds( \
    (const __attribute__((address_space(1))) void*)(g), \
    (__attribute__((address_space(3))) void*)(l), 16, 0, 0)

// ---------- transpose + cast fp32 -> bf16 : out[C][R] = in[R][C] ----------
__global__ __launch_bounds__(256) void k_transpose_cast(
    const float* __restrict__ in, __hip_bfloat16* __restrict__ out,
    int R, int C) {
  __shared__ float t[32][33];
  const int tx = threadIdx.x, ty = threadIdx.y;
  const int c0 = blockIdx.x * 32, r0 = blockIdx.y * 32;
#pragma unroll
  for (int j = 0; j < 4; ++j)
    t[ty + j * 8][tx] = in[(size_t)(r0 + ty + j * 8) * C + c0 + tx];
  __syncthreads();
#pragma unroll
  for (int j = 0; j < 4; ++j) {
    const int oc = ty + j * 8;
    out[(size_t)(c0 + oc) * R + r0 + tx] = __float2bfloat16(t[tx][oc]);
  }
}

// ---------- elementwise cast fp32 -> bf16 (exact-multiple sizes) ----------
__global__ __launch_bounds__(256) void k_cast_bf16(
    const float* __restrict__ in, __hip_bfloat16* __restrict__ out) {
  const int i = (blockIdx.x * 256 + threadIdx.x) * 4;
  const float4 v = *reinterpret_cast<const float4*>(in + i);
  struct B4 { __hip_bfloat16 a, b, c, d; } o;
  o.a = __float2bfloat16(v.x); o.b = __float2bfloat16(v.y);
  o.c = __float2bfloat16(v.z); o.d = __float2bfloat16(v.w);
  *reinterpret_cast<B4*>(out + i) = o;
}

// ---------- LayerNorm rows of [4096][1024], fp32 in -> bf16 out ----------
__global__ __launch_bounds__(256) void k_layernorm(
    const float* __restrict__ x, const float* __restrict__ g,
    const float* __restrict__ b, __hip_bfloat16* __restrict__ out) {
  const int row = blockIdx.x, tid = threadIdx.x;
  const float4 v = reinterpret_cast<const float4*>(x + (size_t)row * DM)[tid];
  float s = v.x + v.y + v.z + v.w;
  __shared__ float r1[4], r2[4];
#pragma unroll
  for (int off = 32; off; off >>= 1) s += __shfl_xor(s, off);
  if ((tid & 63) == 0) r1[tid >> 6] = s;
  __syncthreads();
  const float mu = (r1[0] + r1[1] + r1[2] + r1[3]) * (1.f / DM);
  const float dx = v.x - mu, dy = v.y - mu, dz = v.z - mu, dw = v.w - mu;
  float q = dx * dx + dy * dy + dz * dz + dw * dw;
#pragma unroll
  for (int off = 32; off; off >>= 1) q += __shfl_xor(q, off);
  if ((tid & 63) == 0) r2[tid >> 6] = q;
  __syncthreads();
  const float rs = rsqrtf((r2[0] + r2[1] + r2[2] + r2[3]) * (1.f / DM) + 1e-5f);
  const float4 gv = reinterpret_cast<const float4*>(g)[tid];
  const float4 bv = reinterpret_cast<const float4*>(b)[tid];
  struct B4 { __hip_bfloat16 a, b, c, d; } o;
  o.a = __float2bfloat16(dx * rs * gv.x + bv.x);
  o.b = __float2bfloat16(dy * rs * gv.y + bv.y);
  o.c = __float2bfloat16(dz * rs * gv.z + bv.z);
  o.d = __float2bfloat16(dw * rs * gv.w + bv.w);
  reinterpret_cast<B4*>(out + (size_t)row * DM)[tid] = o;
}

// ---------- generic 128x128 bf16 MFMA GEMM, C = A[M][K] * BT[N][K]^T ----------
// MODE 0: QKV epilogue  MODE 1: R epilogue  MODE 2: fp32 out epilogue
template <int MODE>
__global__ __launch_bounds__(256) void k_gemm_bt(
    const __hip_bfloat16* __restrict__ A, const __hip_bfloat16* __restrict__ BT,
    int M, int N, int K, float* __restrict__ outF,
    __hip_bfloat16* __restrict__ o_qw, __hip_bfloat16* __restrict__ o_qr,
    __hip_bfloat16* __restrict__ o_k, __hip_bfloat16* __restrict__ o_vT,
    const float* __restrict__ rwb, const float* __restrict__ rrb,
    __hip_bfloat16* __restrict__ o_rT) {
  __shared__ __align__(16) __hip_bfloat16 As[128 * 32];
  __shared__ __align__(16) __hip_bfloat16 Bs[128 * 32];
  const int tid = threadIdx.x, lane = tid & 63;
  const int ntn = N >> 7;
  const int m0 = (blockIdx.x / ntn) * 128, n0 = (blockIdx.x % ntn) * 128;
  const int wid = tid >> 6;
  const int wr = (wid >> 1) * 64, wc = (wid & 1) * 64;
  const int fr = lane & 15, fq = lane >> 4;
  const int srow = tid >> 2, scol = (tid & 3) * 8;
  const __hip_bfloat16* aSrc = A + (size_t)(m0 + srow) * K + scol;
  const __hip_bfloat16* bSrc = BT + (size_t)(n0 + srow) * K + scol;
  char* aDst = (char*)As + (tid - lane) * 16;
  char* bDst = (char*)Bs + (tid - lane) * 16;
  f32x4 acc[4][4] = {};
  for (int k0 = 0; k0 < K; k0 += 32) {
    GLL16(aSrc + k0, aDst);
    GLL16(aSrc + (size_t)64 * K + k0, aDst + 4096);
    GLL16(bSrc + k0, bDst);
    GLL16(bSrc + (size_t)64 * K + k0, bDst + 4096);
    __syncthreads();
    bf16x8 af[4], bfr[4];
#pragma unroll
    for (int mi = 0; mi < 4; ++mi)
      af[mi] = ld_bf16x8(As + (wr + mi * 16 + fr) * 32 + fq * 8);
#pragma unroll
    for (int ni = 0; ni < 4; ++ni)
      bfr[ni] = ld_bf16x8(Bs + (wc + ni * 16 + fr) * 32 + fq * 8);
#pragma unroll
    for (int mi = 0; mi < 4; ++mi)
#pragma unroll
      for (int ni = 0; ni < 4; ++ni)
        acc[mi][ni] = __builtin_amdgcn_mfma_f32_16x16x32_bf16(
            af[mi], bfr[ni], acc[mi][ni], 0, 0, 0);
    __syncthreads();
  }
#pragma unroll
  for (int mi = 0; mi < 4; ++mi) {
#pragma unroll
    for (int ni = 0; ni < 4; ++ni) {
#pragma unroll
      for (int j = 0; j < 4; ++j) {
        const int r = m0 + wr + mi * 16 + fq * 4 + j;
        const int c = n0 + wc + ni * 16 + fr;
        const float v = acc[mi][ni][j];
        if (MODE == 2) {
          outF[(size_t)r * N + c] = v;
        } else if (MODE == 1) {
          const int h = c >> 6, d = c & 63;
          o_rT[((size_t)h * TSEQ + r) * DHD + d] = __float2bfloat16(v);
        } else {
          const int t = r >> 1, bb = r & 1;
          if (c < 1024) {
            const int h = c >> 6, d = c & 63;
            const size_t o = (((size_t)(bb * NH + h)) * TSEQ + t) * DHD + d;
            o_qw[o] = __float2bfloat16(v + rwb[c]);
            o_qr[o] = __float2bfloat16(v + rrb[c]);
          } else if (c < 2048) {
            const int e = c - 1024, h = e >> 6, d = e & 63;
            o_k[(((size_t)(bb * NH + h)) * TSEQ + t) * DHD + d] = __float2bfloat16(v);
          } else {
            const int e = c - 2048, h = e >> 6, d = e & 63;
            o_vT[(((size_t)(bb * NH + h)) * DHD + d) * TSEQ + t] = __float2bfloat16(v);
          }
        }
      }
    }
  }
}

// ---------- fused causal rel-attention, swapped core, 2-wave blocks ----------
// Wave = one (head, 16-row q-tile). S^T = mfma(K,Q): lane owns q-row fr.
// Band produced SWAPPED: mfma(R_frag, Qr_frag) -> D[m=16pp+4fq+jj][q=fr],
// stored braw[fr][16pp+4fq] as ONE b128 write; consumer reads
// braw[fr][15-fr+koff] (identical to R5's passing index).
// P packed to 4x b64. V loads issued at iteration top (latency hidden under
// S^T + band + softmax). PV swapped: O^T[d][q=fr]; per-lane alpha/1l.
// Grid 2048 x 128 threads: 2-wave blocks, ~16KB LDS -> fine-grained backfill.
__global__ __launch_bounds__(128) void k_attn(
    const __hip_bfloat16* __restrict__ qw, const __hip_bfloat16* __restrict__ qr,
    const __hip_bfloat16* __restrict__ kb, const __hip_bfloat16* __restrict__ vT,
    const __hip_bfloat16* __restrict__ rT, __hip_bfloat16* __restrict__ av) {
  const int tid = threadIdx.x, w = tid >> 6, lane = tid & 63;
  const int fr = lane & 15, fq = lane >> 4;
  const int bid = blockIdx.x;
  const int xcd = bid & 7, slot = bid >> 3;   // slot 0..255
  const int t = slot * 2 + w;                 // wave-task 0..511
  const int bh = xcd * 4 + (t & 3);           // 4 heads per XCD (L2-local)
  const int bb = bh >> 4, h = bh & 15;
  const int p = 127 - (t >> 2);               // LPT: big tiles first
  const int iw0 = p * 16;
  const int nk = (p >> 2) + 1;
  const size_t bhs = (size_t)bh;
  const __hip_bfloat16* Kp = kb + bhs * TSEQ * DHD;
  const __hip_bfloat16* Vt = vT + bhs * DHD * TSEQ;
  const __hip_bfloat16* Rp = rT + (size_t)h * TSEQ * DHD;
  __shared__ __align__(16) float braw[2][16][88];
  __shared__ __align__(16) __hip_bfloat16 plq[2][16][72];
  const f32x4 zero = {0.f, 0.f, 0.f, 0.f};

  const __hip_bfloat16* qwp = qw + (bhs * TSEQ + iw0 + fr) * DHD + fq * 8;
  const __hip_bfloat16* qrp = qr + (bhs * TSEQ + iw0 + fr) * DHD + fq * 8;
  const bf16x8 qwf0 = ld_bf16x8(qwp), qwf1 = ld_bf16x8(qwp + 32);
  const bf16x8 qrf0 = ld_bf16x8(qrp), qrf1 = ld_bf16x8(qrp + 32);

  f32x4 o[4] = {};
  float mrow = -INFINITY, lrow = 0.f;

  for (int kt = 0; kt < nk; ++kt) {
    const int j0 = kt * 64;
    // ---- V prefetch: issue now, consumed at iteration end ----
    bf16x8 vv[8];
#pragma unroll
    for (int c = 0; c < 2; ++c)
#pragma unroll
      for (int nd = 0; nd < 4; ++nd)
        vv[c * 4 + nd] = ld_bf16x8(Vt + (size_t)(16 * nd + fr) * TSEQ + j0 + 32 * c + 8 * fq);
    // ---- S^T = mfma(K, Q): st[n][j] = S[q=fr][koff=16n+4fq+j] ----
    f32x4 st[4];
    const __hip_bfloat16* kp0 = Kp + (size_t)(j0 + fr) * DHD + fq * 8;
#pragma unroll
    for (int n = 0; n < 4; ++n) {
      st[n] = __builtin_amdgcn_mfma_f32_16x16x32_bf16(ld_bf16x8(kp0 + n * 1024), qwf0, zero, 0, 0, 0);
      st[n] = __builtin_amdgcn_mfma_f32_16x16x32_bf16(ld_bf16x8(kp0 + n * 1024 + 32), qwf1, st[n], 0, 0, 0);
    }
    // ---- band, swapped production: D[m=16pp+4fq+jj][q=fr] = Braw[q][m] ----
    const int base = TSEQ - 16 - iw0 + j0;
#pragma unroll
    for (int pp = 0; pp < 5; ++pp) {
      int idx = base + pp * 16 + fr;
      idx = idx < 0 ? 0 : (idx > TSEQ - 1 ? TSEQ - 1 : idx);  // clamped => masked region only
      const __hip_bfloat16* rp = Rp + (size_t)idx * DHD + fq * 8;
      f32x4 br = __builtin_amdgcn_mfma_f32_16x16x32_bf16(ld_bf16x8(rp), qrf0, zero, 0, 0, 0);
      br = __builtin_amdgcn_mfma_f32_16x16x32_bf16(ld_bf16x8(rp + 32), qrf1, br, 0, 0, 0);
      *reinterpret_cast<f32x4*>(&braw[w][fr][pp * 16 + 4 * fq]) = br;  // b128 write
    }
    // ---- scores + in-register online softmax (q = fr) ----
    const int thr = iw0 + fr - j0;              // unmasked iff koff <= thr
    const float* brd = &braw[w][fr][15 - fr];   // brd[koff] = BD term
    float mx = -INFINITY;
#pragma unroll
    for (int n = 0; n < 4; ++n) {
#pragma unroll
      for (int j = 0; j < 4; ++j) {
        const int koff = 16 * n + 4 * fq + j;
        const float s = (koff > thr) ? -INFINITY : (st[n][j] + brd[koff]) * 0.125f;
        st[n][j] = s;
        mx = fmaxf(mx, s);
      }
    }
    mx = fmaxf(mx, __shfl_xor(mx, 16));
    mx = fmaxf(mx, __shfl_xor(mx, 32));
    const float mn = fmaxf(mrow, mx);
    const float al = __expf(mrow - mn);
    mrow = mn;
    float rs = 0.f;
#pragma unroll
    for (int n = 0; n < 4; ++n)
#pragma unroll
      for (int j = 0; j < 4; ++j) {
        const float pv = __expf(st[n][j] - mn);
        st[n][j] = pv;
        rs += pv;
      }
    rs += __shfl_xor(rs, 16);
    rs += __shfl_xor(rs, 32);
    lrow = lrow * al + rs;
#pragma unroll
    for (int nd = 0; nd < 4; ++nd) o[nd] *= al;   // per-lane scalar (q = fr)
    // ---- P store: packed b64 at P[q=fr][16n+4fq] ----
    struct B4 { __hip_bfloat16 a, b, c, d; };
#pragma unroll
    for (int n = 0; n < 4; ++n) {
      B4 pk;
      pk.a = __float2bfloat16(st[n][0]);
      pk.b = __float2bfloat16(st[n][1]);
      pk.c = __float2bfloat16(st[n][2]);
      pk.d = __float2bfloat16(st[n][3]);
      *reinterpret_cast<B4*>(&plq[w][fr][16 * n + 4 * fq]) = pk;
    }
    // ---- O^T += V^T . P^T : o[nd][j] = O[d=16nd+4fq+j][q=fr] ----
#pragma unroll
    for (int c = 0; c < 2; ++c) {
      const bf16x8 pf = ld_bf16x8(&plq[w][fr][8 * fq + 32 * c]);
#pragma unroll
      for (int nd = 0; nd < 4; ++nd)
        o[nd] = __builtin_amdgcn_mfma_f32_16x16x32_bf16(vv[c * 4 + nd], pf, o[nd], 0, 0, 0);
    }
  }
  // ---- epilogue: per-lane 1/l, packed 8B stores; row i = iw0+fr ----
  const float linv = 1.f / lrow;
  const int i = iw0 + fr;
  struct B4 { __hip_bfloat16 a, b, c, d; };
#pragma unroll
  for (int nd = 0; nd < 4; ++nd) {
    B4 pack;
    pack.a = __float2bfloat16(o[nd][0] * linv);
    pack.b = __float2bfloat16(o[nd][1] * linv);
    pack.c = __float2bfloat16(o[nd][2] * linv);
    pack.d = __float2bfloat16(o[nd][3] * linv);
    *reinterpret_cast<B4*>(av + ((size_t)i * NB + bb) * DM + h * DHD + 16 * nd + 4 * fq) = pack;
  }
}

extern "C" void kernel_launch(void* const* d_in, const int* in_sizes, int n_in,
                              void* d_out, int out_size, void* d_ws, size_t ws_size,
                              hipStream_t stream) {
  (void)in_sizes; (void)n_in; (void)out_size; (void)ws_size;
  const float* x    = (const float*)d_in[0];
  const float* pos  = (const float*)d_in[1];
  const float* ln_g = (const float*)d_in[2];
  const float* ln_b = (const float*)d_in[3];
  const float* Wqkv = (const float*)d_in[4];
  const float* Wr   = (const float*)d_in[5];
  const float* Wo   = (const float*)d_in[6];
  const float* rwb  = (const float*)d_in[7];
  const float* rrb  = (const float*)d_in[8];
  float* out = (float*)d_out;

  char* ws = (char*)d_ws;
  size_t off = 0;
  auto alloc = [&](size_t n) {
    char* p = ws + off; off += (n + 255) & ~(size_t)255; return p;
  };
  __hip_bfloat16* wqkvT = (__hip_bfloat16*)alloc((size_t)3072 * 1024 * 2);
  __hip_bfloat16* wrT   = (__hip_bfloat16*)alloc((size_t)1024 * 1024 * 2);
  __hip_bfloat16* woT   = (__hip_bfloat16*)alloc((size_t)1024 * 1024 * 2);
  __hip_bfloat16* posb  = (__hip_bfloat16*)alloc((size_t)2048 * 1024 * 2);
  __hip_bfloat16* xn    = (__hip_bfloat16*)alloc((size_t)4096 * 1024 * 2);
  __hip_bfloat16* qwb   = (__hip_bfloat16*)alloc((size_t)NB * NH * TSEQ * DHD * 2);
  __hip_bfloat16* qrb   = (__hip_bfloat16*)alloc((size_t)NB * NH * TSEQ * DHD * 2);
  __hip_bfloat16* kbb   = (__hip_bfloat16*)alloc((size_t)NB * NH * TSEQ * DHD * 2);
  __hip_bfloat16* vTb   = (__hip_bfloat16*)alloc((size_t)NB * NH * TSEQ * DHD * 2);
  __hip_bfloat16* rTb   = (__hip_bfloat16*)alloc((size_t)NH * TSEQ * DHD * 2);
  __hip_bfloat16* avb   = (__hip_bfloat16*)alloc((size_t)4096 * 1024 * 2);

  const dim3 tb(32, 8);
  k_transpose_cast<<<dim3(3072 / 32, 1024 / 32), tb, 0, stream>>>(Wqkv, wqkvT, 1024, 3072);
  k_transpose_cast<<<dim3(1024 / 32, 1024 / 32), tb, 0, stream>>>(Wr, wrT, 1024, 1024);
  k_transpose_cast<<<dim3(1024 / 32, 1024 / 32), tb, 0, stream>>>(Wo, woT, 1024, 1024);
  k_cast_bf16<<<(2048 * 1024) / 1024, 256, 0, stream>>>(pos, posb);
  k_layernorm<<<4096, 256, 0, stream>>>(x, ln_g, ln_b, xn);
  k_gemm_bt<0><<<32 * 24, 256, 0, stream>>>(xn, wqkvT, 4096, 3072, 1024,
      nullptr, qwb, qrb, kbb, vTb, rwb, rrb, nullptr);
  k_gemm_bt<1><<<16 * 8, 256, 0, stream>>>(posb, wrT, 2048, 1024, 1024,
      nullptr, nullptr, nullptr, nullptr, nullptr, nullptr, nullptr, rTb);
  k_attn<<<2048, 128, 0, stream>>>(qwb, qrb, kbb, vTb, rTb, avb);
  k_gemm_bt<2><<<32 * 8, 256, 0, stream>>>(avb, woT, 4096, 1024, 1024,
      out, nullptr, nullptr, nullptr, nullptr, nullptr, nullptr, nullptr);
}